// Round 5
// baseline (120.093 us; speedup 1.0000x reference)
//
#include <hip/hip_runtime.h>
#include <hip/hip_bf16.h>
#include <stdint.h>

// B=8, N=1024, D_IN=D_OUT=512, H=8, DH=64, SCALE=8
// Round 5: swapped-operand QK^T (vectorized bias) + LDS P staging in S^T
// layout with scalar-verified f2b packing (cvt_pk/shuffle path removed).

typedef __attribute__((ext_vector_type(4))) float f32x4;
typedef __attribute__((ext_vector_type(8))) short s16x8;
typedef __attribute__((ext_vector_type(4))) unsigned short u16x4;

union FragAB { s16x8 v; u16x4 h[2]; unsigned u[4]; };

#define LOG2E 1.44269504089f
#define QSCALE (0.125f * LOG2E)

__device__ __forceinline__ unsigned short f2b(float f) {
  unsigned u = __builtin_bit_cast(unsigned, f);
  u = (u + 0x7FFFu + ((u >> 16) & 1u)) >> 16;  // RNE
  return (unsigned short)u;
}
__device__ __forceinline__ unsigned pack2(float lo, float hi) {
  return ((unsigned)f2b(hi) << 16) | (unsigned)f2b(lo);
}

// ---------------- merged prep: x->bf16 (blocks 0..4095), W transpose (4096..4351)
__global__ __launch_bounds__(256) void prep_k(const float* __restrict__ x,
                                              unsigned short* __restrict__ xb,
                                              const float* __restrict__ W0,
                                              const float* __restrict__ W1,
                                              const float* __restrict__ W2,
                                              const float* __restrict__ W3,
                                              unsigned short* __restrict__ Wt) {
  __shared__ float ld[64][68];
  const int t = threadIdx.x;
  if (blockIdx.x < 4096) {
    int idx = blockIdx.x * 256 + t;
    f32x4 v = ((const f32x4*)x)[idx];
    u16x4 o;
#pragma unroll
    for (int j = 0; j < 4; j++) o[j] = f2b(v[j]);
    ((u16x4*)xb)[idx] = o;
    return;
  }
  const int bid2 = blockIdx.x - 4096;
  const int widx = bid2 >> 6;
  const int tile = bid2 & 63;
  const int trow = tile >> 3, tcol = tile & 7;
  const float* W = widx == 0 ? W0 : widx == 1 ? W1 : widx == 2 ? W2 : W3;
  const int r = t >> 2, cc = (t & 3) * 16;
  const float* src = W + (size_t)(trow * 64 + r) * 512 + tcol * 64 + cc;
#pragma unroll
  for (int u = 0; u < 4; u++)
    ((f32x4*)&ld[r][cc])[u] = ((const f32x4*)src)[u];
  __syncthreads();
  unsigned short* dst = Wt + ((size_t)widx << 18) + (size_t)(tcol * 64 + r) * 512 +
                        trow * 64 + cc;
#pragma unroll
  for (int u = 0; u < 4; u++) {
    u16x4 o;
#pragma unroll
    for (int e = 0; e < 4; e++) o[e] = f2b(ld[cc + u * 4 + e][r]);
    ((u16x4*)dst)[u] = o;
  }
}

// ---------------- fused QKV GEMM ----------------
__global__ __launch_bounds__(256, 2) void gemm_qkv_k(const unsigned short* __restrict__ A,
                                                     const unsigned short* __restrict__ Bt,
                                                     const float* __restrict__ bq,
                                                     const float* __restrict__ bk,
                                                     const float* __restrict__ bv,
                                                     unsigned short* __restrict__ outp) {
  __shared__ unsigned short At[2][128][36];
  __shared__ unsigned short Bts[2][128][36];
  const int tid = threadIdx.x;
  const int lane = tid & 63;
  const int w = tid >> 6;
  const int wm = w >> 1, wn = w & 1;
  const int g = lane >> 4, c = lane & 15;
  const int bn0 = (blockIdx.x % 12) * 128;
  const int bm0 = (blockIdx.x / 12) * 128;
  const int srow = tid >> 1;
  const int scol = (tid & 1) * 16;

  f32x4 acc[4][4];
#pragma unroll
  for (int i = 0; i < 4; i++)
#pragma unroll
    for (int j = 0; j < 4; j++) acc[i][j] = f32x4{0.f, 0.f, 0.f, 0.f};

  u16x4 ra[4], rb[4];
  auto ld = [&](int kt) {
    const u16x4* pa = (const u16x4*)(A + (size_t)(bm0 + srow) * 512 + kt * 32 + scol);
    const u16x4* pb = (const u16x4*)(Bt + (size_t)(bn0 + srow) * 512 + kt * 32 + scol);
#pragma unroll
    for (int j = 0; j < 4; j++) { ra[j] = pa[j]; rb[j] = pb[j]; }
  };
  auto st = [&](int b) {
    u16x4* da = (u16x4*)&At[b][srow][scol];
    u16x4* db = (u16x4*)&Bts[b][srow][scol];
#pragma unroll
    for (int j = 0; j < 4; j++) { da[j] = ra[j]; db[j] = rb[j]; }
  };

  ld(0); st(0);
  __syncthreads();

  for (int kt = 0; kt < 16; ++kt) {
    const int cb = kt & 1;
    if (kt < 15) ld(kt + 1);

    FragAB af[4], bf[4];
#pragma unroll
    for (int mi = 0; mi < 4; mi++) {
      const u16x4* p = (const u16x4*)&At[cb][wm * 64 + mi * 16 + c][g * 8];
      af[mi].h[0] = p[0]; af[mi].h[1] = p[1];
    }
#pragma unroll
    for (int ni = 0; ni < 4; ni++) {
      const u16x4* p = (const u16x4*)&Bts[cb][wn * 64 + ni * 16 + c][g * 8];
      bf[ni].h[0] = p[0]; bf[ni].h[1] = p[1];
    }
    __builtin_amdgcn_s_setprio(1);
#pragma unroll
    for (int mi = 0; mi < 4; mi++)
#pragma unroll
      for (int ni = 0; ni < 4; ni++)
        acc[mi][ni] = __builtin_amdgcn_mfma_f32_16x16x32_bf16(af[mi].v, bf[ni].v,
                                                              acc[mi][ni], 0, 0, 0);
    __builtin_amdgcn_s_setprio(0);

    if (kt < 15) {
      st(cb ^ 1);
      __syncthreads();
    }
  }

  const int qkv = (bn0 + wn * 64) >> 9;
  const float* bp = qkv == 0 ? bq : (qkv == 1 ? bk : bv);
  const float scale = qkv == 0 ? QSCALE : 1.0f;
#pragma unroll
  for (int mi = 0; mi < 4; mi++) {
#pragma unroll
    for (int ni = 0; ni < 4; ni++) {
      const int col = bn0 + wn * 64 + ni * 16 + c;
      const int c9 = col & 511;
      const float bvv = bp[c9];
#pragma unroll
      for (int m = 0; m < 4; m++) {
        const int row = bm0 + wm * 64 + mi * 16 + g * 4 + m;
        const float v = (acc[mi][ni][m] + bvv) * scale;
        const int b = row >> 10, n = row & 1023;
        const int hh = c9 >> 6, d = col & 63;
        outp[((size_t)qkv << 22) + ((size_t)((b << 3) + hh) << 16) +
             ((size_t)n << 6) + d] = f2b(v);
      }
    }
  }
}

// ---------------- output GEMM ----------------
__global__ __launch_bounds__(256, 2) void gemm_o_k(const unsigned short* __restrict__ A,
                                                   const unsigned short* __restrict__ Bt,
                                                   const float* __restrict__ bias,
                                                   float* __restrict__ outp) {
  __shared__ unsigned short At[2][128][36];
  __shared__ unsigned short Bts[2][128][36];
  const int tid = threadIdx.x;
  const int lane = tid & 63;
  const int w = tid >> 6;
  const int wm = w >> 1, wn = w & 1;
  const int g = lane >> 4, c = lane & 15;
  const int bn0 = (blockIdx.x & 3) * 128;
  const int bm0 = (blockIdx.x >> 2) * 128;
  const int srow = tid >> 1;
  const int scol = (tid & 1) * 16;

  f32x4 acc[4][4];
#pragma unroll
  for (int i = 0; i < 4; i++)
#pragma unroll
    for (int j = 0; j < 4; j++) acc[i][j] = f32x4{0.f, 0.f, 0.f, 0.f};

  u16x4 ra[4], rb[4];
  auto ld = [&](int kt) {
    const u16x4* pa = (const u16x4*)(A + (size_t)(bm0 + srow) * 512 + kt * 32 + scol);
    const u16x4* pb = (const u16x4*)(Bt + (size_t)(bn0 + srow) * 512 + kt * 32 + scol);
#pragma unroll
    for (int j = 0; j < 4; j++) { ra[j] = pa[j]; rb[j] = pb[j]; }
  };
  auto st = [&](int b) {
    u16x4* da = (u16x4*)&At[b][srow][scol];
    u16x4* db = (u16x4*)&Bts[b][srow][scol];
#pragma unroll
    for (int j = 0; j < 4; j++) { da[j] = ra[j]; db[j] = rb[j]; }
  };

  ld(0); st(0);
  __syncthreads();

  for (int kt = 0; kt < 16; ++kt) {
    const int cb = kt & 1;
    if (kt < 15) ld(kt + 1);

    FragAB af[4], bf[4];
#pragma unroll
    for (int mi = 0; mi < 4; mi++) {
      const u16x4* p = (const u16x4*)&At[cb][wm * 64 + mi * 16 + c][g * 8];
      af[mi].h[0] = p[0]; af[mi].h[1] = p[1];
    }
#pragma unroll
    for (int ni = 0; ni < 4; ni++) {
      const u16x4* p = (const u16x4*)&Bts[cb][wn * 64 + ni * 16 + c][g * 8];
      bf[ni].h[0] = p[0]; bf[ni].h[1] = p[1];
    }
    __builtin_amdgcn_s_setprio(1);
#pragma unroll
    for (int mi = 0; mi < 4; mi++)
#pragma unroll
      for (int ni = 0; ni < 4; ni++)
        acc[mi][ni] = __builtin_amdgcn_mfma_f32_16x16x32_bf16(af[mi].v, bf[ni].v,
                                                              acc[mi][ni], 0, 0, 0);
    __builtin_amdgcn_s_setprio(0);

    if (kt < 15) {
      st(cb ^ 1);
      __syncthreads();
    }
  }

#pragma unroll
  for (int mi = 0; mi < 4; mi++) {
#pragma unroll
    for (int ni = 0; ni < 4; ni++) {
      const int col = bn0 + wn * 64 + ni * 16 + c;
      const float bv = bias[col];
#pragma unroll
      for (int m = 0; m < 4; m++) {
        const int row = bm0 + wm * 64 + mi * 16 + g * 4 + m;
        outp[(size_t)row * 512 + col] = acc[mi][ni][m] + bv;
      }
    }
  }
}

// ---------------- flash attention: swapped-QK, S^T-layout LDS P ----------------
// grid (8, 64), block 512 = 8 waves, wave owns 16 q-rows, KV tile 64 dbuf.
__global__ __launch_bounds__(512, 4) void attn_k(const unsigned short* __restrict__ Qb,
                                                 const unsigned short* __restrict__ Kb,
                                                 const unsigned short* __restrict__ Vb,
                                                 const float* __restrict__ pos_bias,
                                                 unsigned short* __restrict__ ao) {
  __shared__ unsigned short Klds[2][64][68];
  __shared__ unsigned short Vtlds[2][64][68];  // [d][kv_row]
  __shared__ unsigned short Plds[8][16][68];   // [wave][q-local][kv]

  const int tid = threadIdx.x;
  const int lane = tid & 63;
  const int w = tid >> 6;
  const int g = lane >> 4, c = lane & 15;
  const int qt = blockIdx.x;
  const int bh = blockIdx.y;
  const int h = bh & 7;
  const size_t bhq = (size_t)bh << 16;
  const int q0 = qt * 128 + w * 16;

  // Q fragments (B-operand): lane (c,g) holds Q[q0+c][kk*32+g*8 ..+7]
  FragAB aq[2];
#pragma unroll
  for (int kk = 0; kk < 2; kk++) {
    const u16x4* p =
        (const u16x4*)(Qb + bhq + ((size_t)(q0 + c) << 6) + kk * 32 + g * 8);
    aq[kk].h[0] = p[0]; aq[kk].h[1] = p[1];
  }

  f32x4 acco[4];  // O[q=(g*4+m)][d=nd*16+c]
#pragma unroll
  for (int nd = 0; nd < 4; nd++) acco[nd] = f32x4{0.f, 0.f, 0.f, 0.f};
  float lsum = 0.f;  // denominator partial for q = q0 + c

  const int krow = tid >> 4;
  const int kslot = (tid & 15) * 4;
  const int vd = tid & 63;
  const int vs = w;

  u16x4 kr[2], vr[2];
  auto stageLoad = [&](int k0n) {
    kr[0] = *(const u16x4*)(Kb + bhq + ((size_t)(k0n + krow) << 6) + kslot);
    kr[1] = *(const u16x4*)(Kb + bhq + ((size_t)(k0n + krow + 32) << 6) + kslot);
    const unsigned short* pv = Vb + bhq + ((size_t)(k0n + vs * 8) << 6) + vd;
    union { unsigned short s[8]; u16x4 v[2]; } vv;
#pragma unroll
    for (int j = 0; j < 8; j++) vv.s[j] = pv[(size_t)j << 6];
    vr[0] = vv.v[0]; vr[1] = vv.v[1];
  };
  auto stageWrite = [&](int b) {
    *(u16x4*)&Klds[b][krow][kslot] = kr[0];
    *(u16x4*)&Klds[b][krow + 32][kslot] = kr[1];
    *(u16x4*)&Vtlds[b][vd][vs * 8] = vr[0];
    *(u16x4*)&Vtlds[b][vd][vs * 8 + 4] = vr[1];
  };

  // bias: lane (c,g) needs pos_bias[h][q0+c][k0+16ni+4g .. +3] -> f32x4 per 16-k
  const float* pbB = pos_bias + ((size_t)h << 20) + ((size_t)(q0 + c) << 10) + 4 * g;

  stageLoad(0);
  stageWrite(0);
  __syncthreads();

  f32x4 pbX[4], pbY[4];
#pragma unroll
  for (int ni = 0; ni < 4; ni++) pbX[ni] = *(const f32x4*)(pbB + 16 * ni);

  auto body = [&](int kt, f32x4 (&pbu)[4], f32x4 (&pbn)[4]) {
    const int buf = kt & 1;
    const int k0 = kt * 64;
    if (kt < 15) {
      stageLoad(k0 + 64);
#pragma unroll
      for (int ni = 0; ni < 4; ni++)
        pbn[ni] = *(const f32x4*)(pbB + k0 + 64 + 16 * ni);
    }

    // S^T = K @ Q^T : lane (c,g) reg r = S[q=q0+c][k0+16ni+4g+r]
    FragAB bk[4][2];
#pragma unroll
    for (int ni = 0; ni < 4; ni++)
#pragma unroll
      for (int kk = 0; kk < 2; kk++) {
        const u16x4* p = (const u16x4*)&Klds[buf][ni * 16 + c][kk * 32 + g * 8];
        bk[ni][kk].h[0] = p[0]; bk[ni][kk].h[1] = p[1];
      }
    f32x4 sT[4];
    __builtin_amdgcn_s_setprio(1);
#pragma unroll
    for (int ni = 0; ni < 4; ni++) {
      f32x4 s = f32x4{0.f, 0.f, 0.f, 0.f};
      s = __builtin_amdgcn_mfma_f32_16x16x32_bf16(bk[ni][0].v, aq[0].v, s, 0, 0, 0);
      s = __builtin_amdgcn_mfma_f32_16x16x32_bf16(bk[ni][1].v, aq[1].v, s, 0, 0, 0);
      sT[ni] = s;
    }
    __builtin_amdgcn_s_setprio(0);

    // p = exp2(s + bias*log2e); write P[q=c][k] as packed dwords (S^T layout)
#pragma unroll
    for (int ni = 0; ni < 4; ni++) {
      const float p0 = __builtin_amdgcn_exp2f(fmaf(pbu[ni][0], LOG2E, sT[ni][0]));
      const float p1 = __builtin_amdgcn_exp2f(fmaf(pbu[ni][1], LOG2E, sT[ni][1]));
      const float p2 = __builtin_amdgcn_exp2f(fmaf(pbu[ni][2], LOG2E, sT[ni][2]));
      const float p3 = __builtin_amdgcn_exp2f(fmaf(pbu[ni][3], LOG2E, sT[ni][3]));
      lsum += (p0 + p1) + (p2 + p3);
      *(unsigned*)&Plds[w][c][16 * ni + 4 * g]     = pack2(p0, p1);
      *(unsigned*)&Plds[w][c][16 * ni + 4 * g + 2] = pack2(p2, p3);
    }

    asm volatile("s_waitcnt lgkmcnt(0)" ::: "memory");

    // O += P @ V  (A-frag: P[q=c][kc*32+g*8+j], same pattern as r1-3)
    FragAB paf[2], vb2[4][2];
#pragma unroll
    for (int kc = 0; kc < 2; kc++) {
      const u16x4* p = (const u16x4*)&Plds[w][c][kc * 32 + g * 8];
      paf[kc].h[0] = p[0]; paf[kc].h[1] = p[1];
    }
#pragma unroll
    for (int nd = 0; nd < 4; nd++)
#pragma unroll
      for (int kc = 0; kc < 2; kc++) {
        const u16x4* p = (const u16x4*)&Vtlds[buf][nd * 16 + c][kc * 32 + g * 8];
        vb2[nd][kc].h[0] = p[0]; vb2[nd][kc].h[1] = p[1];
      }
    __builtin_amdgcn_s_setprio(1);
#pragma unroll
    for (int nd = 0; nd < 4; nd++) {
      acco[nd] = __builtin_amdgcn_mfma_f32_16x16x32_bf16(paf[0].v, vb2[nd][0].v,
                                                         acco[nd], 0, 0, 0);
      acco[nd] = __builtin_amdgcn_mfma_f32_16x16x32_bf16(paf[1].v, vb2[nd][1].v,
                                                         acco[nd], 0, 0, 0);
    }
    __builtin_amdgcn_s_setprio(0);

    if (kt < 15) {
      stageWrite(buf ^ 1);
      __syncthreads();
    }
  };

  for (int kt2 = 0; kt2 < 16; kt2 += 2) {
    body(kt2, pbX, pbY);
    body(kt2 + 1, pbY, pbX);
  }

  // epilogue: denominator for q=q0+c lives across lanes {c, c+16, c+32, c+48}
  float l = lsum;
  l += __shfl_xor(l, 16);
  l += __shfl_xor(l, 32);
  const float inv_c = 1.f / l;
  const int b = bh >> 3;
#pragma unroll
  for (int m = 0; m < 4; m++) {
    const float invm = __shfl(inv_c, g * 4 + m);  // lane g*4+m holds q=q0+g*4+m
    const int n = q0 + g * 4 + m;
#pragma unroll
    for (int nd = 0; nd < 4; nd++) {
      ao[((size_t)(b * 1024 + n) << 9) + h * 64 + nd * 16 + c] =
          f2b(acco[nd][m] * invm);
    }
  }
}

// ---------------- launch ----------------
extern "C" void kernel_launch(void* const* d_in, const int* in_sizes, int n_in,
                              void* d_out, int out_size, void* d_ws, size_t ws_size,
                              hipStream_t stream) {
  (void)in_sizes; (void)n_in; (void)out_size; (void)ws_size;
  const float* x  = (const float*)d_in[0];
  const float* Wq = (const float*)d_in[1];
  const float* bq = (const float*)d_in[2];
  const float* Wk = (const float*)d_in[3];
  const float* bk = (const float*)d_in[4];
  const float* Wv = (const float*)d_in[5];
  const float* bv = (const float*)d_in[6];
  const float* Wo = (const float*)d_in[7];
  const float* bo = (const float*)d_in[8];
  const float* pbias = (const float*)d_in[9];

  char* p = (char*)d_ws;
  unsigned short* xb  = (unsigned short*)p; p += (size_t)8192 * 512 * 2;
  unsigned short* WT  = (unsigned short*)p; p += (size_t)4 * 512 * 512 * 2;
  unsigned short* Qb  = (unsigned short*)p; p += (size_t)3 * 64 * 1024 * 64 * 2;
  unsigned short* AO  = (unsigned short*)p;

  unsigned short* WoT = WT + (size_t)3 * 512 * 512;
  unsigned short* Kb  = Qb + (size_t)64 * 1024 * 64;
  unsigned short* Vb  = Kb + (size_t)64 * 1024 * 64;

  prep_k<<<4352, 256, 0, stream>>>(x, xb, Wq, Wk, Wv, Wo, WT);
  gemm_qkv_k<<<768, 256, 0, stream>>>(xb, WT, bq, bk, bv, Qb);
  attn_k<<<dim3(8, 64), 512, 0, stream>>>(Qb, Kb, Vb, pbias, AO);
  gemm_o_k<<<256, 256, 0, stream>>>(AO, WoT, bo, (float*)d_out);
}

// Round 6
// 89.303 us; speedup vs baseline: 1.3448x; 1.3448x over previous
//
#include <hip/hip_runtime.h>
#include <hip/hip_bf16.h>
#include <stdint.h>

// B=8, N=1024, D_IN=D_OUT=512, H=8, DH=64, SCALE=8
// Round 6: round-5 minus the spill (in-loop vectorized bias load, no
// ping-pong state) + XCD-aware block remap so each XCD sees one head's bias.

typedef __attribute__((ext_vector_type(4))) float f32x4;
typedef __attribute__((ext_vector_type(8))) short s16x8;
typedef __attribute__((ext_vector_type(4))) unsigned short u16x4;

union FragAB { s16x8 v; u16x4 h[2]; unsigned u[4]; };

#define LOG2E 1.44269504089f
#define QSCALE (0.125f * LOG2E)

__device__ __forceinline__ unsigned short f2b(float f) {
  unsigned u = __builtin_bit_cast(unsigned, f);
  u = (u + 0x7FFFu + ((u >> 16) & 1u)) >> 16;  // RNE
  return (unsigned short)u;
}
__device__ __forceinline__ unsigned pack2(float lo, float hi) {
  return ((unsigned)f2b(hi) << 16) | (unsigned)f2b(lo);
}

// ---------------- merged prep: x->bf16 (blocks 0..4095), W transpose (4096..4351)
__global__ __launch_bounds__(256) void prep_k(const float* __restrict__ x,
                                              unsigned short* __restrict__ xb,
                                              const float* __restrict__ W0,
                                              const float* __restrict__ W1,
                                              const float* __restrict__ W2,
                                              const float* __restrict__ W3,
                                              unsigned short* __restrict__ Wt) {
  __shared__ float ld[64][68];
  const int t = threadIdx.x;
  if (blockIdx.x < 4096) {
    int idx = blockIdx.x * 256 + t;
    f32x4 v = ((const f32x4*)x)[idx];
    u16x4 o;
#pragma unroll
    for (int j = 0; j < 4; j++) o[j] = f2b(v[j]);
    ((u16x4*)xb)[idx] = o;
    return;
  }
  const int bid2 = blockIdx.x - 4096;
  const int widx = bid2 >> 6;
  const int tile = bid2 & 63;
  const int trow = tile >> 3, tcol = tile & 7;
  const float* W = widx == 0 ? W0 : widx == 1 ? W1 : widx == 2 ? W2 : W3;
  const int r = t >> 2, cc = (t & 3) * 16;
  const float* src = W + (size_t)(trow * 64 + r) * 512 + tcol * 64 + cc;
#pragma unroll
  for (int u = 0; u < 4; u++)
    ((f32x4*)&ld[r][cc])[u] = ((const f32x4*)src)[u];
  __syncthreads();
  unsigned short* dst = Wt + ((size_t)widx << 18) + (size_t)(tcol * 64 + r) * 512 +
                        trow * 64 + cc;
#pragma unroll
  for (int u = 0; u < 4; u++) {
    u16x4 o;
#pragma unroll
    for (int e = 0; e < 4; e++) o[e] = f2b(ld[cc + u * 4 + e][r]);
    ((u16x4*)dst)[u] = o;
  }
}

// ---------------- fused QKV GEMM ----------------
__global__ __launch_bounds__(256, 2) void gemm_qkv_k(const unsigned short* __restrict__ A,
                                                     const unsigned short* __restrict__ Bt,
                                                     const float* __restrict__ bq,
                                                     const float* __restrict__ bk,
                                                     const float* __restrict__ bv,
                                                     unsigned short* __restrict__ outp) {
  __shared__ unsigned short At[2][128][36];
  __shared__ unsigned short Bts[2][128][36];
  const int tid = threadIdx.x;
  const int lane = tid & 63;
  const int w = tid >> 6;
  const int wm = w >> 1, wn = w & 1;
  const int g = lane >> 4, c = lane & 15;
  const int bn0 = (blockIdx.x % 12) * 128;
  const int bm0 = (blockIdx.x / 12) * 128;
  const int srow = tid >> 1;
  const int scol = (tid & 1) * 16;

  f32x4 acc[4][4];
#pragma unroll
  for (int i = 0; i < 4; i++)
#pragma unroll
    for (int j = 0; j < 4; j++) acc[i][j] = f32x4{0.f, 0.f, 0.f, 0.f};

  u16x4 ra[4], rb[4];
  auto ld = [&](int kt) {
    const u16x4* pa = (const u16x4*)(A + (size_t)(bm0 + srow) * 512 + kt * 32 + scol);
    const u16x4* pb = (const u16x4*)(Bt + (size_t)(bn0 + srow) * 512 + kt * 32 + scol);
#pragma unroll
    for (int j = 0; j < 4; j++) { ra[j] = pa[j]; rb[j] = pb[j]; }
  };
  auto st = [&](int b) {
    u16x4* da = (u16x4*)&At[b][srow][scol];
    u16x4* db = (u16x4*)&Bts[b][srow][scol];
#pragma unroll
    for (int j = 0; j < 4; j++) { da[j] = ra[j]; db[j] = rb[j]; }
  };

  ld(0); st(0);
  __syncthreads();

  for (int kt = 0; kt < 16; ++kt) {
    const int cb = kt & 1;
    if (kt < 15) ld(kt + 1);

    FragAB af[4], bf[4];
#pragma unroll
    for (int mi = 0; mi < 4; mi++) {
      const u16x4* p = (const u16x4*)&At[cb][wm * 64 + mi * 16 + c][g * 8];
      af[mi].h[0] = p[0]; af[mi].h[1] = p[1];
    }
#pragma unroll
    for (int ni = 0; ni < 4; ni++) {
      const u16x4* p = (const u16x4*)&Bts[cb][wn * 64 + ni * 16 + c][g * 8];
      bf[ni].h[0] = p[0]; bf[ni].h[1] = p[1];
    }
    __builtin_amdgcn_s_setprio(1);
#pragma unroll
    for (int mi = 0; mi < 4; mi++)
#pragma unroll
      for (int ni = 0; ni < 4; ni++)
        acc[mi][ni] = __builtin_amdgcn_mfma_f32_16x16x32_bf16(af[mi].v, bf[ni].v,
                                                              acc[mi][ni], 0, 0, 0);
    __builtin_amdgcn_s_setprio(0);

    if (kt < 15) {
      st(cb ^ 1);
      __syncthreads();
    }
  }

  const int qkv = (bn0 + wn * 64) >> 9;
  const float* bp = qkv == 0 ? bq : (qkv == 1 ? bk : bv);
  const float scale = qkv == 0 ? QSCALE : 1.0f;
#pragma unroll
  for (int mi = 0; mi < 4; mi++) {
#pragma unroll
    for (int ni = 0; ni < 4; ni++) {
      const int col = bn0 + wn * 64 + ni * 16 + c;
      const int c9 = col & 511;
      const float bvv = bp[c9];
#pragma unroll
      for (int m = 0; m < 4; m++) {
        const int row = bm0 + wm * 64 + mi * 16 + g * 4 + m;
        const float v = (acc[mi][ni][m] + bvv) * scale;
        const int b = row >> 10, n = row & 1023;
        const int hh = c9 >> 6, d = col & 63;
        outp[((size_t)qkv << 22) + ((size_t)((b << 3) + hh) << 16) +
             ((size_t)n << 6) + d] = f2b(v);
      }
    }
  }
}

// ---------------- output GEMM ----------------
__global__ __launch_bounds__(256, 2) void gemm_o_k(const unsigned short* __restrict__ A,
                                                   const unsigned short* __restrict__ Bt,
                                                   const float* __restrict__ bias,
                                                   float* __restrict__ outp) {
  __shared__ unsigned short At[2][128][36];
  __shared__ unsigned short Bts[2][128][36];
  const int tid = threadIdx.x;
  const int lane = tid & 63;
  const int w = tid >> 6;
  const int wm = w >> 1, wn = w & 1;
  const int g = lane >> 4, c = lane & 15;
  const int bn0 = (blockIdx.x & 3) * 128;
  const int bm0 = (blockIdx.x >> 2) * 128;
  const int srow = tid >> 1;
  const int scol = (tid & 1) * 16;

  f32x4 acc[4][4];
#pragma unroll
  for (int i = 0; i < 4; i++)
#pragma unroll
    for (int j = 0; j < 4; j++) acc[i][j] = f32x4{0.f, 0.f, 0.f, 0.f};

  u16x4 ra[4], rb[4];
  auto ld = [&](int kt) {
    const u16x4* pa = (const u16x4*)(A + (size_t)(bm0 + srow) * 512 + kt * 32 + scol);
    const u16x4* pb = (const u16x4*)(Bt + (size_t)(bn0 + srow) * 512 + kt * 32 + scol);
#pragma unroll
    for (int j = 0; j < 4; j++) { ra[j] = pa[j]; rb[j] = pb[j]; }
  };
  auto st = [&](int b) {
    u16x4* da = (u16x4*)&At[b][srow][scol];
    u16x4* db = (u16x4*)&Bts[b][srow][scol];
#pragma unroll
    for (int j = 0; j < 4; j++) { da[j] = ra[j]; db[j] = rb[j]; }
  };

  ld(0); st(0);
  __syncthreads();

  for (int kt = 0; kt < 16; ++kt) {
    const int cb = kt & 1;
    if (kt < 15) ld(kt + 1);

    FragAB af[4], bf[4];
#pragma unroll
    for (int mi = 0; mi < 4; mi++) {
      const u16x4* p = (const u16x4*)&At[cb][wm * 64 + mi * 16 + c][g * 8];
      af[mi].h[0] = p[0]; af[mi].h[1] = p[1];
    }
#pragma unroll
    for (int ni = 0; ni < 4; ni++) {
      const u16x4* p = (const u16x4*)&Bts[cb][wn * 64 + ni * 16 + c][g * 8];
      bf[ni].h[0] = p[0]; bf[ni].h[1] = p[1];
    }
    __builtin_amdgcn_s_setprio(1);
#pragma unroll
    for (int mi = 0; mi < 4; mi++)
#pragma unroll
      for (int ni = 0; ni < 4; ni++)
        acc[mi][ni] = __builtin_amdgcn_mfma_f32_16x16x32_bf16(af[mi].v, bf[ni].v,
                                                              acc[mi][ni], 0, 0, 0);
    __builtin_amdgcn_s_setprio(0);

    if (kt < 15) {
      st(cb ^ 1);
      __syncthreads();
    }
  }

#pragma unroll
  for (int mi = 0; mi < 4; mi++) {
#pragma unroll
    for (int ni = 0; ni < 4; ni++) {
      const int col = bn0 + wn * 64 + ni * 16 + c;
      const float bv = bias[col];
#pragma unroll
      for (int m = 0; m < 4; m++) {
        const int row = bm0 + wm * 64 + mi * 16 + g * 4 + m;
        outp[(size_t)row * 512 + col] = acc[mi][ni][m] + bv;
      }
    }
  }
}

// ---------------- flash attention: swapped-QK, S^T-layout LDS P ----------------
// grid 512 linear; XCD remap: h = L&7 so each XCD works one head's bias slab.
__global__ __launch_bounds__(512, 4) void attn_k(const unsigned short* __restrict__ Qb,
                                                 const unsigned short* __restrict__ Kb,
                                                 const unsigned short* __restrict__ Vb,
                                                 const float* __restrict__ pos_bias,
                                                 unsigned short* __restrict__ ao) {
  __shared__ unsigned short Klds[2][64][68];
  __shared__ unsigned short Vtlds[2][64][68];  // [d][kv_row]
  __shared__ unsigned short Plds[8][16][68];   // [wave][q-local][kv]

  const int tid = threadIdx.x;
  const int lane = tid & 63;
  const int w = tid >> 6;
  const int g = lane >> 4, c = lane & 15;
  // XCD-aware remap (bijective): XCD(L)=L%8 sees only head h=L&7.
  const int L = blockIdx.x;
  const int qt = L >> 6;
  const int bh = (L & 7) + 8 * ((L >> 3) & 7);
  const int h = bh & 7;
  const size_t bhq = (size_t)bh << 16;
  const int q0 = qt * 128 + w * 16;

  // Q fragments (B-operand): lane (c,g) holds Q[q0+c][kk*32+g*8 ..+7]
  FragAB aq[2];
#pragma unroll
  for (int kk = 0; kk < 2; kk++) {
    const u16x4* p =
        (const u16x4*)(Qb + bhq + ((size_t)(q0 + c) << 6) + kk * 32 + g * 8);
    aq[kk].h[0] = p[0]; aq[kk].h[1] = p[1];
  }

  f32x4 acco[4];  // O[q=(g*4+m)][d=nd*16+c]
#pragma unroll
  for (int nd = 0; nd < 4; nd++) acco[nd] = f32x4{0.f, 0.f, 0.f, 0.f};
  float lsum = 0.f;  // denominator partial for q = q0 + c

  const int krow = tid >> 4;
  const int kslot = (tid & 15) * 4;
  const int vd = tid & 63;
  const int vs = w;

  u16x4 kr[2], vr[2];
  auto stageLoad = [&](int k0n) {
    kr[0] = *(const u16x4*)(Kb + bhq + ((size_t)(k0n + krow) << 6) + kslot);
    kr[1] = *(const u16x4*)(Kb + bhq + ((size_t)(k0n + krow + 32) << 6) + kslot);
    const unsigned short* pv = Vb + bhq + ((size_t)(k0n + vs * 8) << 6) + vd;
    union { unsigned short s[8]; u16x4 v[2]; } vv;
#pragma unroll
    for (int j = 0; j < 8; j++) vv.s[j] = pv[(size_t)j << 6];
    vr[0] = vv.v[0]; vr[1] = vv.v[1];
  };
  auto stageWrite = [&](int b) {
    *(u16x4*)&Klds[b][krow][kslot] = kr[0];
    *(u16x4*)&Klds[b][krow + 32][kslot] = kr[1];
    *(u16x4*)&Vtlds[b][vd][vs * 8] = vr[0];
    *(u16x4*)&Vtlds[b][vd][vs * 8 + 4] = vr[1];
  };

  // bias: lane (c,g) needs pos_bias[h][q0+c][k0+16ni+4g .. +3]
  const float* pbB = pos_bias + ((size_t)h << 20) + ((size_t)(q0 + c) << 10) + 4 * g;

  stageLoad(0);
  stageWrite(0);
  __syncthreads();

  for (int kt = 0; kt < 16; ++kt) {
    const int buf = kt & 1;
    const int k0 = kt << 6;
    if (kt < 15) stageLoad(k0 + 64);

    // current tile's bias: 4x dwordx4, issued before LDS reads (L2 latency
    // hides under K-frag ds_reads + QK MFMA). No cross-iter live state.
    f32x4 pb[4];
#pragma unroll
    for (int ni = 0; ni < 4; ni++) pb[ni] = *(const f32x4*)(pbB + k0 + 16 * ni);

    // S^T = K @ Q^T : lane (c,g) reg r = S[q=q0+c][k0+16ni+4g+r]
    FragAB bk[4][2];
#pragma unroll
    for (int ni = 0; ni < 4; ni++)
#pragma unroll
      for (int kk = 0; kk < 2; kk++) {
        const u16x4* p = (const u16x4*)&Klds[buf][ni * 16 + c][kk * 32 + g * 8];
        bk[ni][kk].h[0] = p[0]; bk[ni][kk].h[1] = p[1];
      }
    f32x4 sT[4];
    __builtin_amdgcn_s_setprio(1);
#pragma unroll
    for (int ni = 0; ni < 4; ni++) {
      f32x4 s = f32x4{0.f, 0.f, 0.f, 0.f};
      s = __builtin_amdgcn_mfma_f32_16x16x32_bf16(bk[ni][0].v, aq[0].v, s, 0, 0, 0);
      s = __builtin_amdgcn_mfma_f32_16x16x32_bf16(bk[ni][1].v, aq[1].v, s, 0, 0, 0);
      sT[ni] = s;
    }
    __builtin_amdgcn_s_setprio(0);

    // p = exp2(s + bias*log2e); write P[q=c][k] as packed dwords (S^T layout)
#pragma unroll
    for (int ni = 0; ni < 4; ni++) {
      const float p0 = __builtin_amdgcn_exp2f(fmaf(pb[ni][0], LOG2E, sT[ni][0]));
      const float p1 = __builtin_amdgcn_exp2f(fmaf(pb[ni][1], LOG2E, sT[ni][1]));
      const float p2 = __builtin_amdgcn_exp2f(fmaf(pb[ni][2], LOG2E, sT[ni][2]));
      const float p3 = __builtin_amdgcn_exp2f(fmaf(pb[ni][3], LOG2E, sT[ni][3]));
      lsum += (p0 + p1) + (p2 + p3);
      *(unsigned*)&Plds[w][c][16 * ni + 4 * g]     = pack2(p0, p1);
      *(unsigned*)&Plds[w][c][16 * ni + 4 * g + 2] = pack2(p2, p3);
    }

    asm volatile("s_waitcnt lgkmcnt(0)" ::: "memory");

    // O += P @ V  (A-frag: P[q=c][kc*32+g*8+j])
    FragAB paf[2], vb2[4][2];
#pragma unroll
    for (int kc = 0; kc < 2; kc++) {
      const u16x4* p = (const u16x4*)&Plds[w][c][kc * 32 + g * 8];
      paf[kc].h[0] = p[0]; paf[kc].h[1] = p[1];
    }
#pragma unroll
    for (int nd = 0; nd < 4; nd++)
#pragma unroll
      for (int kc = 0; kc < 2; kc++) {
        const u16x4* p = (const u16x4*)&Vtlds[buf][nd * 16 + c][kc * 32 + g * 8];
        vb2[nd][kc].h[0] = p[0]; vb2[nd][kc].h[1] = p[1];
      }
    __builtin_amdgcn_s_setprio(1);
#pragma unroll
    for (int nd = 0; nd < 4; nd++) {
      acco[nd] = __builtin_amdgcn_mfma_f32_16x16x32_bf16(paf[0].v, vb2[nd][0].v,
                                                         acco[nd], 0, 0, 0);
      acco[nd] = __builtin_amdgcn_mfma_f32_16x16x32_bf16(paf[1].v, vb2[nd][1].v,
                                                         acco[nd], 0, 0, 0);
    }
    __builtin_amdgcn_s_setprio(0);

    if (kt < 15) {
      stageWrite(buf ^ 1);
      __syncthreads();
    }
  }

  // epilogue: denominator for q=q0+c lives across lanes {c, c+16, c+32, c+48}
  float l = lsum;
  l += __shfl_xor(l, 16);
  l += __shfl_xor(l, 32);
  const float inv_c = 1.f / l;
  const int b = bh >> 3;
#pragma unroll
  for (int m = 0; m < 4; m++) {
    const float invm = __shfl(inv_c, g * 4 + m);  // lane g*4+m holds q=q0+g*4+m
    const int n = q0 + g * 4 + m;
#pragma unroll
    for (int nd = 0; nd < 4; nd++) {
      ao[((size_t)(b * 1024 + n) << 9) + h * 64 + nd * 16 + c] =
          f2b(acco[nd][m] * invm);
    }
  }
}

// ---------------- launch ----------------
extern "C" void kernel_launch(void* const* d_in, const int* in_sizes, int n_in,
                              void* d_out, int out_size, void* d_ws, size_t ws_size,
                              hipStream_t stream) {
  (void)in_sizes; (void)n_in; (void)out_size; (void)ws_size;
  const float* x  = (const float*)d_in[0];
  const float* Wq = (const float*)d_in[1];
  const float* bq = (const float*)d_in[2];
  const float* Wk = (const float*)d_in[3];
  const float* bk = (const float*)d_in[4];
  const float* Wv = (const float*)d_in[5];
  const float* bv = (const float*)d_in[6];
  const float* Wo = (const float*)d_in[7];
  const float* bo = (const float*)d_in[8];
  const float* pbias = (const float*)d_in[9];

  char* p = (char*)d_ws;
  unsigned short* xb  = (unsigned short*)p; p += (size_t)8192 * 512 * 2;
  unsigned short* WT  = (unsigned short*)p; p += (size_t)4 * 512 * 512 * 2;
  unsigned short* Qb  = (unsigned short*)p; p += (size_t)3 * 64 * 1024 * 64 * 2;
  unsigned short* AO  = (unsigned short*)p;

  unsigned short* WoT = WT + (size_t)3 * 512 * 512;
  unsigned short* Kb  = Qb + (size_t)64 * 1024 * 64;
  unsigned short* Vb  = Kb + (size_t)64 * 1024 * 64;

  prep_k<<<4352, 256, 0, stream>>>(x, xb, Wq, Wk, Wv, Wo, WT);
  gemm_qkv_k<<<768, 256, 0, stream>>>(xb, WT, bq, bk, bv, Qb);
  attn_k<<<512, 512, 0, stream>>>(Qb, Kb, Vb, pbias, AO);
  gemm_o_k<<<256, 256, 0, stream>>>(AO, WoT, bo, (float*)d_out);
}

// Round 7
// 88.094 us; speedup vs baseline: 1.3632x; 1.0137x over previous
//
#include <hip/hip_runtime.h>
#include <hip/hip_bf16.h>
#include <stdint.h>

// B=8, N=1024, D_IN=D_OUT=512, H=8, DH=64, SCALE=8
// Round 7: attn waves own 32 q-rows (halves per-FLOP LDS frag traffic);
// 4-wave blocks; same verified fragment algebra with mi in {0,1}.

typedef __attribute__((ext_vector_type(4))) float f32x4;
typedef __attribute__((ext_vector_type(8))) short s16x8;
typedef __attribute__((ext_vector_type(4))) unsigned short u16x4;
typedef __attribute__((ext_vector_type(8))) unsigned short u16x8;

union FragAB { s16x8 v; u16x4 h[2]; unsigned u[4]; };

#define LOG2E 1.44269504089f
#define QSCALE (0.125f * LOG2E)

__device__ __forceinline__ unsigned short f2b(float f) {
  unsigned u = __builtin_bit_cast(unsigned, f);
  u = (u + 0x7FFFu + ((u >> 16) & 1u)) >> 16;  // RNE
  return (unsigned short)u;
}
__device__ __forceinline__ unsigned pack2(float lo, float hi) {
  return ((unsigned)f2b(hi) << 16) | (unsigned)f2b(lo);
}

// ---------------- merged prep: x->bf16 (blocks 0..4095), W transpose (4096..4351)
__global__ __launch_bounds__(256) void prep_k(const float* __restrict__ x,
                                              unsigned short* __restrict__ xb,
                                              const float* __restrict__ W0,
                                              const float* __restrict__ W1,
                                              const float* __restrict__ W2,
                                              const float* __restrict__ W3,
                                              unsigned short* __restrict__ Wt) {
  __shared__ float ld[64][68];
  const int t = threadIdx.x;
  if (blockIdx.x < 4096) {
    int idx = blockIdx.x * 256 + t;
    f32x4 v = ((const f32x4*)x)[idx];
    u16x4 o;
#pragma unroll
    for (int j = 0; j < 4; j++) o[j] = f2b(v[j]);
    ((u16x4*)xb)[idx] = o;
    return;
  }
  const int bid2 = blockIdx.x - 4096;
  const int widx = bid2 >> 6;
  const int tile = bid2 & 63;
  const int trow = tile >> 3, tcol = tile & 7;
  const float* W = widx == 0 ? W0 : widx == 1 ? W1 : widx == 2 ? W2 : W3;
  const int r = t >> 2, cc = (t & 3) * 16;
  const float* src = W + (size_t)(trow * 64 + r) * 512 + tcol * 64 + cc;
#pragma unroll
  for (int u = 0; u < 4; u++)
    ((f32x4*)&ld[r][cc])[u] = ((const f32x4*)src)[u];
  __syncthreads();
  unsigned short* dst = Wt + ((size_t)widx << 18) + (size_t)(tcol * 64 + r) * 512 +
                        trow * 64 + cc;
#pragma unroll
  for (int u = 0; u < 4; u++) {
    u16x4 o;
#pragma unroll
    for (int e = 0; e < 4; e++) o[e] = f2b(ld[cc + u * 4 + e][r]);
    ((u16x4*)dst)[u] = o;
  }
}

// ---------------- fused QKV GEMM ----------------
__global__ __launch_bounds__(256, 2) void gemm_qkv_k(const unsigned short* __restrict__ A,
                                                     const unsigned short* __restrict__ Bt,
                                                     const float* __restrict__ bq,
                                                     const float* __restrict__ bk,
                                                     const float* __restrict__ bv,
                                                     unsigned short* __restrict__ outp) {
  __shared__ unsigned short At[2][128][36];
  __shared__ unsigned short Bts[2][128][36];
  const int tid = threadIdx.x;
  const int lane = tid & 63;
  const int w = tid >> 6;
  const int wm = w >> 1, wn = w & 1;
  const int g = lane >> 4, c = lane & 15;
  const int bn0 = (blockIdx.x % 12) * 128;
  const int bm0 = (blockIdx.x / 12) * 128;
  const int srow = tid >> 1;
  const int scol = (tid & 1) * 16;

  f32x4 acc[4][4];
#pragma unroll
  for (int i = 0; i < 4; i++)
#pragma unroll
    for (int j = 0; j < 4; j++) acc[i][j] = f32x4{0.f, 0.f, 0.f, 0.f};

  u16x4 ra[4], rb[4];
  auto ld = [&](int kt) {
    const u16x4* pa = (const u16x4*)(A + (size_t)(bm0 + srow) * 512 + kt * 32 + scol);
    const u16x4* pb = (const u16x4*)(Bt + (size_t)(bn0 + srow) * 512 + kt * 32 + scol);
#pragma unroll
    for (int j = 0; j < 4; j++) { ra[j] = pa[j]; rb[j] = pb[j]; }
  };
  auto st = [&](int b) {
    u16x4* da = (u16x4*)&At[b][srow][scol];
    u16x4* db = (u16x4*)&Bts[b][srow][scol];
#pragma unroll
    for (int j = 0; j < 4; j++) { da[j] = ra[j]; db[j] = rb[j]; }
  };

  ld(0); st(0);
  __syncthreads();

  for (int kt = 0; kt < 16; ++kt) {
    const int cb = kt & 1;
    if (kt < 15) ld(kt + 1);

    FragAB af[4], bf[4];
#pragma unroll
    for (int mi = 0; mi < 4; mi++) {
      const u16x4* p = (const u16x4*)&At[cb][wm * 64 + mi * 16 + c][g * 8];
      af[mi].h[0] = p[0]; af[mi].h[1] = p[1];
    }
#pragma unroll
    for (int ni = 0; ni < 4; ni++) {
      const u16x4* p = (const u16x4*)&Bts[cb][wn * 64 + ni * 16 + c][g * 8];
      bf[ni].h[0] = p[0]; bf[ni].h[1] = p[1];
    }
    __builtin_amdgcn_s_setprio(1);
#pragma unroll
    for (int mi = 0; mi < 4; mi++)
#pragma unroll
      for (int ni = 0; ni < 4; ni++)
        acc[mi][ni] = __builtin_amdgcn_mfma_f32_16x16x32_bf16(af[mi].v, bf[ni].v,
                                                              acc[mi][ni], 0, 0, 0);
    __builtin_amdgcn_s_setprio(0);

    if (kt < 15) {
      st(cb ^ 1);
      __syncthreads();
    }
  }

  const int qkv = (bn0 + wn * 64) >> 9;
  const float* bp = qkv == 0 ? bq : (qkv == 1 ? bk : bv);
  const float scale = qkv == 0 ? QSCALE : 1.0f;
#pragma unroll
  for (int mi = 0; mi < 4; mi++) {
#pragma unroll
    for (int ni = 0; ni < 4; ni++) {
      const int col = bn0 + wn * 64 + ni * 16 + c;
      const int c9 = col & 511;
      const float bvv = bp[c9];
#pragma unroll
      for (int m = 0; m < 4; m++) {
        const int row = bm0 + wm * 64 + mi * 16 + g * 4 + m;
        const float v = (acc[mi][ni][m] + bvv) * scale;
        const int b = row >> 10, n = row & 1023;
        const int hh = c9 >> 6, d = col & 63;
        outp[((size_t)qkv << 22) + ((size_t)((b << 3) + hh) << 16) +
             ((size_t)n << 6) + d] = f2b(v);
      }
    }
  }
}

// ---------------- output GEMM ----------------
__global__ __launch_bounds__(256, 2) void gemm_o_k(const unsigned short* __restrict__ A,
                                                   const unsigned short* __restrict__ Bt,
                                                   const float* __restrict__ bias,
                                                   float* __restrict__ outp) {
  __shared__ unsigned short At[2][128][36];
  __shared__ unsigned short Bts[2][128][36];
  const int tid = threadIdx.x;
  const int lane = tid & 63;
  const int w = tid >> 6;
  const int wm = w >> 1, wn = w & 1;
  const int g = lane >> 4, c = lane & 15;
  const int bn0 = (blockIdx.x & 3) * 128;
  const int bm0 = (blockIdx.x >> 2) * 128;
  const int srow = tid >> 1;
  const int scol = (tid & 1) * 16;

  f32x4 acc[4][4];
#pragma unroll
  for (int i = 0; i < 4; i++)
#pragma unroll
    for (int j = 0; j < 4; j++) acc[i][j] = f32x4{0.f, 0.f, 0.f, 0.f};

  u16x4 ra[4], rb[4];
  auto ld = [&](int kt) {
    const u16x4* pa = (const u16x4*)(A + (size_t)(bm0 + srow) * 512 + kt * 32 + scol);
    const u16x4* pb = (const u16x4*)(Bt + (size_t)(bn0 + srow) * 512 + kt * 32 + scol);
#pragma unroll
    for (int j = 0; j < 4; j++) { ra[j] = pa[j]; rb[j] = pb[j]; }
  };
  auto st = [&](int b) {
    u16x4* da = (u16x4*)&At[b][srow][scol];
    u16x4* db = (u16x4*)&Bts[b][srow][scol];
#pragma unroll
    for (int j = 0; j < 4; j++) { da[j] = ra[j]; db[j] = rb[j]; }
  };

  ld(0); st(0);
  __syncthreads();

  for (int kt = 0; kt < 16; ++kt) {
    const int cb = kt & 1;
    if (kt < 15) ld(kt + 1);

    FragAB af[4], bf[4];
#pragma unroll
    for (int mi = 0; mi < 4; mi++) {
      const u16x4* p = (const u16x4*)&At[cb][wm * 64 + mi * 16 + c][g * 8];
      af[mi].h[0] = p[0]; af[mi].h[1] = p[1];
    }
#pragma unroll
    for (int ni = 0; ni < 4; ni++) {
      const u16x4* p = (const u16x4*)&Bts[cb][wn * 64 + ni * 16 + c][g * 8];
      bf[ni].h[0] = p[0]; bf[ni].h[1] = p[1];
    }
    __builtin_amdgcn_s_setprio(1);
#pragma unroll
    for (int mi = 0; mi < 4; mi++)
#pragma unroll
      for (int ni = 0; ni < 4; ni++)
        acc[mi][ni] = __builtin_amdgcn_mfma_f32_16x16x32_bf16(af[mi].v, bf[ni].v,
                                                              acc[mi][ni], 0, 0, 0);
    __builtin_amdgcn_s_setprio(0);

    if (kt < 15) {
      st(cb ^ 1);
      __syncthreads();
    }
  }

#pragma unroll
  for (int mi = 0; mi < 4; mi++) {
#pragma unroll
    for (int ni = 0; ni < 4; ni++) {
      const int col = bn0 + wn * 64 + ni * 16 + c;
      const float bv = bias[col];
#pragma unroll
      for (int m = 0; m < 4; m++) {
        const int row = bm0 + wm * 64 + mi * 16 + g * 4 + m;
        outp[(size_t)row * 512 + col] = acc[mi][ni][m] + bv;
      }
    }
  }
}

// ---------------- flash attention: swapped-QK, 32 q-rows per wave ----------------
// grid 512 linear (XCD remap); block 256 = 4 waves; wave owns 32 q-rows.
__global__ __launch_bounds__(256, 2) void attn_k(const unsigned short* __restrict__ Qb,
                                                 const unsigned short* __restrict__ Kb,
                                                 const unsigned short* __restrict__ Vb,
                                                 const float* __restrict__ pos_bias,
                                                 unsigned short* __restrict__ ao) {
  __shared__ unsigned short Klds[2][64][68];
  __shared__ unsigned short Vtlds[2][64][68];  // [d][kv_row]
  __shared__ unsigned short Plds[4][32][68];   // [wave][q-local][kv]

  const int tid = threadIdx.x;
  const int lane = tid & 63;
  const int w = tid >> 6;                      // 0..3
  const int g = lane >> 4, c = lane & 15;
  // XCD-aware remap (bijective): XCD(L)=L%8 sees only head h=L&7.
  const int L = blockIdx.x;
  const int qt = L >> 6;
  const int bh = (L & 7) + 8 * ((L >> 3) & 7);
  const int h = bh & 7;
  const size_t bhq = (size_t)bh << 16;
  const int q0 = qt * 128 + w * 32;            // wave's 32 q rows

  // Q fragments (B-operand): lane (c,g) holds Q[q0+mi*16+c][kk*32+g*8 ..+7]
  FragAB aq[2][2];
#pragma unroll
  for (int mi = 0; mi < 2; mi++)
#pragma unroll
    for (int kk = 0; kk < 2; kk++) {
      const u16x4* p = (const u16x4*)(Qb + bhq + ((size_t)(q0 + mi * 16 + c) << 6) +
                                      kk * 32 + g * 8);
      aq[mi][kk].h[0] = p[0]; aq[mi][kk].h[1] = p[1];
    }

  f32x4 acco[2][4];  // O[q=mi*16+(g*4+m)][d=nd*16+c]
#pragma unroll
  for (int mi = 0; mi < 2; mi++)
#pragma unroll
    for (int nd = 0; nd < 4; nd++) acco[mi][nd] = f32x4{0.f, 0.f, 0.f, 0.f};
  float lsum[2] = {0.f, 0.f};  // denominator partial for q = q0 + mi*16 + c

  // staging geometry (256 threads)
  const int krow = tid >> 3;        // 0..31
  const int kcol = (tid & 7) * 8;   // elem offset, 16B chunks
  const int vd = tid & 63;          // d
  const int vs = tid >> 6;          // kv segment of 16

  u16x8 kr0, kr1;
  union { unsigned short s[16]; u16x8 v[2]; } vv;
  auto stageLoad = [&](int k0n) {
    kr0 = *(const u16x8*)(Kb + bhq + ((size_t)(k0n + krow) << 6) + kcol);
    kr1 = *(const u16x8*)(Kb + bhq + ((size_t)(k0n + krow + 32) << 6) + kcol);
    const unsigned short* pv = Vb + bhq + ((size_t)(k0n + vs * 16) << 6) + vd;
#pragma unroll
    for (int j = 0; j < 16; j++) vv.s[j] = pv[(size_t)j << 6];
  };
  auto stageWrite = [&](int b) {
    *(u16x8*)&Klds[b][krow][kcol] = kr0;
    *(u16x8*)&Klds[b][krow + 32][kcol] = kr1;
    *(u16x8*)&Vtlds[b][vd][vs * 16] = vv.v[0];
    *(u16x8*)&Vtlds[b][vd][vs * 16 + 8] = vv.v[1];
  };

  // bias: lane (c,g) needs pos_bias[h][q0+mi*16+c][k0+16ni+4g .. +3]
  const float* pbB = pos_bias + ((size_t)h << 20) + ((size_t)(q0 + c) << 10) + 4 * g;

  stageLoad(0);
  stageWrite(0);
  __syncthreads();

  for (int kt = 0; kt < 16; ++kt) {
    const int buf = kt & 1;
    const int k0 = kt << 6;
    if (kt < 15) stageLoad(k0 + 64);

    // current tile's bias: 8x dwordx4, issued before LDS reads
    f32x4 pb[2][4];
#pragma unroll
    for (int mi = 0; mi < 2; mi++)
#pragma unroll
      for (int ni = 0; ni < 4; ni++)
        pb[mi][ni] = *(const f32x4*)(pbB + (mi << 14) + k0 + 16 * ni);

    // S^T = K @ Q^T : lane (c,g) reg r = S[q=q0+mi*16+c][k0+16ni+4g+r]
    FragAB bk[4][2];
#pragma unroll
    for (int ni = 0; ni < 4; ni++)
#pragma unroll
      for (int kk = 0; kk < 2; kk++) {
        const u16x4* p = (const u16x4*)&Klds[buf][ni * 16 + c][kk * 32 + g * 8];
        bk[ni][kk].h[0] = p[0]; bk[ni][kk].h[1] = p[1];
      }
    f32x4 sT[2][4];
    __builtin_amdgcn_s_setprio(1);
#pragma unroll
    for (int mi = 0; mi < 2; mi++)
#pragma unroll
      for (int ni = 0; ni < 4; ni++) {
        f32x4 s = f32x4{0.f, 0.f, 0.f, 0.f};
        s = __builtin_amdgcn_mfma_f32_16x16x32_bf16(bk[ni][0].v, aq[mi][0].v, s, 0, 0, 0);
        s = __builtin_amdgcn_mfma_f32_16x16x32_bf16(bk[ni][1].v, aq[mi][1].v, s, 0, 0, 0);
        sT[mi][ni] = s;
      }
    __builtin_amdgcn_s_setprio(0);

    // p = exp2(s + bias*log2e); write P[q][k] as packed b64 (S^T layout)
#pragma unroll
    for (int mi = 0; mi < 2; mi++)
#pragma unroll
      for (int ni = 0; ni < 4; ni++) {
        const float p0 = __builtin_amdgcn_exp2f(fmaf(pb[mi][ni][0], LOG2E, sT[mi][ni][0]));
        const float p1 = __builtin_amdgcn_exp2f(fmaf(pb[mi][ni][1], LOG2E, sT[mi][ni][1]));
        const float p2 = __builtin_amdgcn_exp2f(fmaf(pb[mi][ni][2], LOG2E, sT[mi][ni][2]));
        const float p3 = __builtin_amdgcn_exp2f(fmaf(pb[mi][ni][3], LOG2E, sT[mi][ni][3]));
        lsum[mi] += (p0 + p1) + (p2 + p3);
        uint2 two;
        two.x = pack2(p0, p1);
        two.y = pack2(p2, p3);
        *(uint2*)&Plds[w][mi * 16 + c][16 * ni + 4 * g] = two;
      }

    asm volatile("s_waitcnt lgkmcnt(0)" ::: "memory");

    // O += P @ V  (A-frag: P[q][kc*32+g*8+j]; V-frags shared across mi)
    FragAB paf[2][2], vb2[4][2];
#pragma unroll
    for (int mi = 0; mi < 2; mi++)
#pragma unroll
      for (int kc = 0; kc < 2; kc++) {
        const u16x4* p = (const u16x4*)&Plds[w][mi * 16 + c][kc * 32 + g * 8];
        paf[mi][kc].h[0] = p[0]; paf[mi][kc].h[1] = p[1];
      }
#pragma unroll
    for (int nd = 0; nd < 4; nd++)
#pragma unroll
      for (int kc = 0; kc < 2; kc++) {
        const u16x4* p = (const u16x4*)&Vtlds[buf][nd * 16 + c][kc * 32 + g * 8];
        vb2[nd][kc].h[0] = p[0]; vb2[nd][kc].h[1] = p[1];
      }
    __builtin_amdgcn_s_setprio(1);
#pragma unroll
    for (int mi = 0; mi < 2; mi++)
#pragma unroll
      for (int nd = 0; nd < 4; nd++) {
        acco[mi][nd] = __builtin_amdgcn_mfma_f32_16x16x32_bf16(paf[mi][0].v, vb2[nd][0].v,
                                                               acco[mi][nd], 0, 0, 0);
        acco[mi][nd] = __builtin_amdgcn_mfma_f32_16x16x32_bf16(paf[mi][1].v, vb2[nd][1].v,
                                                               acco[mi][nd], 0, 0, 0);
      }
    __builtin_amdgcn_s_setprio(0);

    if (kt < 15) {
      stageWrite(buf ^ 1);
      __syncthreads();
    }
  }

  // epilogue: per mi, denominator for q=q0+mi*16+c across lanes {c,c+16,c+32,c+48}
  const int b = bh >> 3;
#pragma unroll
  for (int mi = 0; mi < 2; mi++) {
    float l = lsum[mi];
    l += __shfl_xor(l, 16);
    l += __shfl_xor(l, 32);
    const float inv_c = 1.f / l;
#pragma unroll
    for (int m = 0; m < 4; m++) {
      const float invm = __shfl(inv_c, g * 4 + m);  // lane g*4+m holds q-col g*4+m
      const int n = q0 + mi * 16 + g * 4 + m;
#pragma unroll
      for (int nd = 0; nd < 4; nd++) {
        ao[((size_t)(b * 1024 + n) << 9) + h * 64 + nd * 16 + c] =
            f2b(acco[mi][nd][m] * invm);
      }
    }
  }
}

// ---------------- launch ----------------
extern "C" void kernel_launch(void* const* d_in, const int* in_sizes, int n_in,
                              void* d_out, int out_size, void* d_ws, size_t ws_size,
                              hipStream_t stream) {
  (void)in_sizes; (void)n_in; (void)out_size; (void)ws_size;
  const float* x  = (const float*)d_in[0];
  const float* Wq = (const float*)d_in[1];
  const float* bq = (const float*)d_in[2];
  const float* Wk = (const float*)d_in[3];
  const float* bk = (const float*)d_in[4];
  const float* Wv = (const float*)d_in[5];
  const float* bv = (const float*)d_in[6];
  const float* Wo = (const float*)d_in[7];
  const float* bo = (const float*)d_in[8];
  const float* pbias = (const float*)d_in[9];

  char* p = (char*)d_ws;
  unsigned short* xb  = (unsigned short*)p; p += (size_t)8192 * 512 * 2;
  unsigned short* WT  = (unsigned short*)p; p += (size_t)4 * 512 * 512 * 2;
  unsigned short* Qb  = (unsigned short*)p; p += (size_t)3 * 64 * 1024 * 64 * 2;
  unsigned short* AO  = (unsigned short*)p;

  unsigned short* WoT = WT + (size_t)3 * 512 * 512;
  unsigned short* Kb  = Qb + (size_t)64 * 1024 * 64;
  unsigned short* Vb  = Kb + (size_t)64 * 1024 * 64;

  prep_k<<<4352, 256, 0, stream>>>(x, xb, Wq, Wk, Wv, Wo, WT);
  gemm_qkv_k<<<768, 256, 0, stream>>>(xb, WT, bq, bk, bv, Qb);
  attn_k<<<512, 256, 0, stream>>>(Qb, Kb, Vb, pbias, AO);
  gemm_o_k<<<256, 256, 0, stream>>>(AO, WoT, bo, (float*)d_out);
}